// Round 9
// baseline (253.957 us; speedup 1.0000x reference)
//
#include <hip/hip_runtime.h>
#include <math.h>

// GMMflow_fast: B=2048, M=1024, D=64.  R9 = R8 fused into ONE kernel with
// manual grid barriers (co-residency proven: 512 blocks @ __launch_bounds__(256,2),
// 70.4KB LDS <= 80KB -> 2 blocks/CU on 256 CUs; spin barrier cannot deadlock).
//   Phase A (full-grid prep, 2 m/block): a,p' bf16 hi/lo -> B1; K,g bf16 -> VT; q f32.
//   [grid barrier 1: release/acquire, counter -> 512]
//   Phase B (main, grid 32x16): GEMM1 3-pass bf16 hi/lo K=128 (A1=[x^2|x] in-kernel);
//     w=exp(clip(-0.5*(C1+q)))*Lam; norm=shfl-reduce of bf16(w); GEMM2 single bf16.
//     Partials: S1|S2 bf16, norms f32.
//   [grid barrier 2: counter -> 1024]
//   Phase C (full-grid finalize, 131072 threads): u=(x*S1+S2)/n.
// R6 lesson: reductions/prep need full-grid parallelism. R7 lesson: no redundant
// per-block prep. R8 numerics preserved bit-for-bit (absmax 0.03125).

#define B_N 2048
#define M_N 1024
#define NSPLIT 16
#define BT 64
#define MS 64

typedef short bf16x8 __attribute__((ext_vector_type(8)));
typedef float f32x4 __attribute__((ext_vector_type(4)));

static __device__ __forceinline__ unsigned short bf16rn(float f) {
    union { float f; unsigned u; } v; v.f = f;
    unsigned r = v.u + 0x7FFF + ((v.u >> 16) & 1);
    return (unsigned short)(r >> 16);
}
static __device__ __forceinline__ float bf2f(unsigned short h) {
    union { unsigned u; float f; } v; v.u = ((unsigned)h) << 16;
    return v.f;
}
static __device__ __forceinline__ void st4(unsigned short* p, unsigned short a,
                                           unsigned short b, unsigned short c, unsigned short d) {
    union { unsigned short u[4]; float2 f; } t;
    t.u[0] = a; t.u[1] = b; t.u[2] = c; t.u[3] = d;
    *(float2*)p = t.f;
}

// release/acquire grid barrier; monotone target, counter memset to 0 per launch.
static __device__ __forceinline__ void grid_barrier(int* cnt, int target, int tid) {
    __syncthreads();
    if (tid == 0) {
        __threadfence();                 // release: partials/prep visible device-wide
        atomicAdd(cnt, 1);
        while (__hip_atomic_load(cnt, __ATOMIC_ACQUIRE, __HIP_MEMORY_SCOPE_AGENT) < target)
            __builtin_amdgcn_s_sleep(2);
    }
    __syncthreads();
    __threadfence();                     // acquire: don't serve stale L1/L2 lines
}

// grid (32,16) = 512 blocks, 256 thr, ~70 KB LDS, 2 blocks/CU (all co-resident).
__global__ __launch_bounds__(256, 2)
void gmm_fused_kernel(const float* __restrict__ X,
                      const float* __restrict__ Mu0, const float* __restrict__ Mu1,
                      const float* __restrict__ S0, const float* __restrict__ S1,
                      const float* __restrict__ Lam,
                      const float* __restrict__ T, const float* __restrict__ E,
                      unsigned short* __restrict__ B1h, unsigned short* __restrict__ B1l,
                      unsigned short* __restrict__ VTh, float* __restrict__ qArr,
                      unsigned short* __restrict__ partBF, float* __restrict__ partN,
                      int* __restrict__ cnt, float* __restrict__ out) {
    __shared__ __align__(16) char smem_raw[70144];
    unsigned short* sm = (unsigned short*)smem_raw;
    unsigned short* sA1h = sm;                // 8704 us
    unsigned short* sA1l = sm + 8704;
    unsigned short* sB1h = sm + 17408;
    unsigned short* sB1l = sm + 26112;        // region end 34816 us
    unsigned short* sV   = sm;                // overlay on A: 128x72 = 9216 us
    unsigned short* sW   = sm + 17408;        // overlay on B: 64x72 = 4608 us
    float* sQ = (float*)(smem_raw + 69632);
    float* sL = (float*)(smem_raw + 69888);

    const int tid  = threadIdx.x;
    const int bid  = blockIdx.y * 32 + blockIdx.x;   // 0..511
    const int Boff = blockIdx.x * BT;
    const int Moff = blockIdx.y * MS;
    const int w    = tid >> 6;
    const int lane = tid & 63;
    const int c = lane & 15, q = lane >> 4;
    const int wb = w >> 1;     // b-half
    const int wm = w & 1;      // GEMM1 m-half / GEMM2 n-half

    // ================= Phase A: full-grid prep, 2 m per block =================
    if (tid < 128) {
        const int mi = tid >> 6, d = tid & 63;
        const int m = bid * 2 + mi;
        const float t = T[0], e = E[0];
        const float eps2 = e * e, eps4 = eps2 * eps2, omt = 1.f - t;
        int idx = m * 64 + d;
        float s0 = S0[idx], s1 = S1[idx];
        float mu0 = Mu0[idx], mu1 = Mu1[idx];
        float Ds = sqrtf(4.f * s0 * s1 + eps4);
        float Cs = 0.5f * (Ds - eps2);
        float sig = omt * omt * s0 + t * t * s1 + 2.f * t * omt * (Cs + 0.5f * eps2);
        float St = (t * s1 + omt * Cs) - (omt * s0 + t * Cs) - eps2 * t;
        float a = 1.f / sig;
        float K = St * a;
        float mut = omt * mu0 + t * mu1;
        float pp = -2.f * mut * a;
        float g = (mu1 - mu0) - K * mut;
        unsigned short ah = bf16rn(a);
        B1h[m * 128 + d] = ah;
        B1l[m * 128 + d] = bf16rn(a - bf2f(ah));
        unsigned short ph = bf16rn(pp);
        B1h[m * 128 + 64 + d] = ph;
        B1l[m * 128 + 64 + d] = bf16rn(pp - bf2f(ph));
        VTh[d * M_N + m]        = bf16rn(K);   // VT rows n=0..63  (K)
        VTh[(64 + d) * M_N + m] = bf16rn(g);   // VT rows n=64..127 (g)
        float qd = mut * mut * a + __logf(sig);
        #pragma unroll
        for (int off = 32; off > 0; off >>= 1) qd += __shfl_xor(qd, off, 64);
        if (d == 0) qArr[m] = qd;
    }

    grid_barrier(cnt, 512, tid);

    // ================= Phase B: main (identical to R8) =================
    {
        const float4* X4 = (const float4*)X;
        #pragma unroll
        for (int it = 0; it < 4; it++) {
            int i = it * 256 + tid;            // 64 b x 16 f4
            int b = i >> 4, dq4 = i & 15;
            float4 xv = X4[(size_t)(Boff + b) * 16 + dq4];
            float xs[4] = {xv.x, xv.y, xv.z, xv.w};
            unsigned short yh[4], yl[4], xh[4], xl[4];
            #pragma unroll
            for (int k = 0; k < 4; k++) {
                float y = xs[k] * xs[k];
                yh[k] = bf16rn(y);  yl[k] = bf16rn(y - bf2f(yh[k]));
                xh[k] = bf16rn(xs[k]);  xl[k] = bf16rn(xs[k] - bf2f(xh[k]));
            }
            int base = b * 136 + 4 * dq4;
            st4(sA1h + base, yh[0], yh[1], yh[2], yh[3]);
            st4(sA1l + base, yl[0], yl[1], yl[2], yl[3]);
            st4(sA1h + base + 64, xh[0], xh[1], xh[2], xh[3]);
            st4(sA1l + base + 64, xl[0], xl[1], xl[2], xl[3]);
        }
        const float4* gBh = (const float4*)B1h + (size_t)Moff * 16;
        const float4* gBl = (const float4*)B1l + (size_t)Moff * 16;
        #pragma unroll
        for (int it = 0; it < 4; it++) {
            int i = it * 256 + tid;            // 64 m x 16 f4
            int row = i >> 4, cc = i & 15;
            *(float4*)(sB1h + row * 136 + cc * 8) = gBh[row * 16 + cc];
            *(float4*)(sB1l + row * 136 + cc * 8) = gBl[row * 16 + cc];
        }
        if (tid < 64) sQ[tid] = qArr[Moff + tid];
        else if (tid < 128) sL[tid - 64] = Lam[Moff + tid - 64];
    }
    __syncthreads();

    // GEMM1: wave quadrant 32b x 32m, K=128, 3 hi/lo passes
    f32x4 acc1[2][2];
    #pragma unroll
    for (int i = 0; i < 2; i++)
        #pragma unroll
        for (int j = 0; j < 2; j++) acc1[i][j] = (f32x4){0.f, 0.f, 0.f, 0.f};
    #pragma unroll
    for (int ks = 0; ks < 4; ks++) {
        bf16x8 Ah[2], Al[2], Bh[2], Bl[2];
        #pragma unroll
        for (int i = 0; i < 2; i++) {
            int row = wb * 32 + i * 16 + c;
            Ah[i] = *(const bf16x8*)(sA1h + row * 136 + ks * 32 + q * 8);
            Al[i] = *(const bf16x8*)(sA1l + row * 136 + ks * 32 + q * 8);
        }
        #pragma unroll
        for (int j = 0; j < 2; j++) {
            int row = wm * 32 + j * 16 + c;
            Bh[j] = *(const bf16x8*)(sB1h + row * 136 + ks * 32 + q * 8);
            Bl[j] = *(const bf16x8*)(sB1l + row * 136 + ks * 32 + q * 8);
        }
        #pragma unroll
        for (int i = 0; i < 2; i++)
            #pragma unroll
            for (int j = 0; j < 2; j++) {
                acc1[i][j] = __builtin_amdgcn_mfma_f32_16x16x32_bf16(Ah[i], Bh[j], acc1[i][j], 0, 0, 0);
                acc1[i][j] = __builtin_amdgcn_mfma_f32_16x16x32_bf16(Ah[i], Bl[j], acc1[i][j], 0, 0, 0);
                acc1[i][j] = __builtin_amdgcn_mfma_f32_16x16x32_bf16(Al[i], Bh[j], acc1[i][j], 0, 0, 0);
            }
    }
    __syncthreads();   // A/B regions dead -> overlays

    // stage V (bf16) + compute W + consistent norm
    {
        const float4* gV = (const float4*)VTh;   // row stride 128 f4
        int mo8 = Moff >> 3;
        #pragma unroll
        for (int it = 0; it < 4; it++) {
            int i = it * 256 + tid;              // 128 n x 8 f4
            int row = i >> 3, cc = i & 7;
            *(float4*)(sV + row * 72 + cc * 8) = gV[(size_t)row * 128 + mo8 + cc];
        }
        float nsum[2][4];
        #pragma unroll
        for (int i = 0; i < 2; i++)
            #pragma unroll
            for (int r = 0; r < 4; r++) nsum[i][r] = 0.f;
        #pragma unroll
        for (int i = 0; i < 2; i++)
            #pragma unroll
            for (int j = 0; j < 2; j++) {
                int m = wm * 32 + j * 16 + c;
                float qm = sQ[m], lm = sL[m];
                #pragma unroll
                for (int r = 0; r < 4; r++) {
                    int bl = wb * 32 + i * 16 + q * 4 + r;
                    float lw = -0.5f * (acc1[i][j][r] + qm);
                    lw = fminf(50.f, fmaxf(-50.f, lw));
                    float wf = __expf(lw) * lm;
                    unsigned short wh = bf16rn(wf);
                    sW[bl * 72 + m] = wh;
                    nsum[i][r] += bf2f(wh);
                }
            }
        #pragma unroll
        for (int mask = 1; mask <= 8; mask <<= 1)
            #pragma unroll
            for (int i = 0; i < 2; i++)
                #pragma unroll
                for (int r = 0; r < 4; r++)
                    nsum[i][r] += __shfl_xor(nsum[i][r], mask, 64);
        if (c == 0) {
            #pragma unroll
            for (int i = 0; i < 2; i++)
                #pragma unroll
                for (int r = 0; r < 4; r++) {
                    int b = Boff + wb * 32 + i * 16 + q * 4 + r;
                    partN[((size_t)blockIdx.y * B_N + b) * 2 + wm] = nsum[i][r];
                }
        }
    }
    __syncthreads();

    // GEMM2: wave 32b x 64n, K=64, single pass
    f32x4 acc2[2][4];
    #pragma unroll
    for (int i = 0; i < 2; i++)
        #pragma unroll
        for (int j = 0; j < 4; j++) acc2[i][j] = (f32x4){0.f, 0.f, 0.f, 0.f};
    #pragma unroll
    for (int ks = 0; ks < 2; ks++) {
        bf16x8 Wf[2], Vf[4];
        #pragma unroll
        for (int i = 0; i < 2; i++) {
            int row = wb * 32 + i * 16 + c;
            Wf[i] = *(const bf16x8*)(sW + row * 72 + ks * 32 + q * 8);
        }
        #pragma unroll
        for (int j = 0; j < 4; j++) {
            int row = wm * 64 + j * 16 + c;
            Vf[j] = *(const bf16x8*)(sV + row * 72 + ks * 32 + q * 8);
        }
        #pragma unroll
        for (int i = 0; i < 2; i++)
            #pragma unroll
            for (int j = 0; j < 4; j++)
                acc2[i][j] = __builtin_amdgcn_mfma_f32_16x16x32_bf16(Wf[i], Vf[j], acc2[i][j], 0, 0, 0);
    }

    // partial S1|S2 writes (bf16)
    #pragma unroll
    for (int i = 0; i < 2; i++)
        #pragma unroll
        for (int j = 0; j < 4; j++) {
            #pragma unroll
            for (int r = 0; r < 4; r++) {
                int b = Boff + wb * 32 + i * 16 + q * 4 + r;
                int n = wm * 64 + j * 16 + c;
                partBF[((size_t)blockIdx.y * B_N + b) * 128 + n] = bf16rn(acc2[i][j][r]);
            }
        }

    grid_barrier(cnt, 1024, tid);

    // ================= Phase C: full-grid finalize (131072 threads) =================
    {
        int gid = bid * 256 + tid;      // b x d
        int b = gid >> 6, d = gid & 63;
        float a1 = 0.f, a2 = 0.f, nn = 0.f;
        #pragma unroll
        for (int s = 0; s < NSPLIT; s++) {
            const unsigned short* row = partBF + ((size_t)s * B_N + b) * 128;
            a1 += bf2f(row[d]);
            a2 += bf2f(row[64 + d]);
            float2 nv = *(const float2*)(partN + ((size_t)s * B_N + b) * 2);
            nn += nv.x + nv.y;
        }
        float rn = 1.f / nn;
        out[gid] = (X[gid] * a1 + a2) * rn;
    }
}

extern "C" void kernel_launch(void* const* d_in, const int* in_sizes, int n_in,
                              void* d_out, int out_size, void* d_ws, size_t ws_size,
                              hipStream_t stream) {
    (void)in_sizes; (void)n_in; (void)out_size; (void)ws_size;
    const float* X   = (const float*)d_in[0];
    const float* Mu0 = (const float*)d_in[1];
    const float* Mu1 = (const float*)d_in[2];
    const float* S0  = (const float*)d_in[3];
    const float* S1  = (const float*)d_in[4];
    const float* Lam = (const float*)d_in[5];
    const float* T   = (const float*)d_in[6];
    const float* E   = (const float*)d_in[7];

    char* ws = (char*)d_ws;
    int*            cnt   = (int*)ws;                           // 4 B (pad 256)
    unsigned short* B1h   = (unsigned short*)(ws + 256);        // 256 KB
    unsigned short* B1l   = (unsigned short*)(ws + 256 + 262144);
    unsigned short* VTh   = (unsigned short*)(ws + 256 + 524288);
    float*          qArr  = (float*)(ws + 256 + 786432);        // 4 KB
    unsigned short* partBF= (unsigned short*)(ws + 256 + 790528);      // 8.39 MB
    float*          partN = (float*)(ws + 256 + 790528 + 8388608);     // 512 KB

    hipMemsetAsync(cnt, 0, 4, stream);
    dim3 grid(B_N / BT, NSPLIT);
    gmm_fused_kernel<<<grid, 256, 0, stream>>>(X, Mu0, Mu1, S0, S1, Lam, T, E,
                                               B1h, B1l, VTh, qArr, partBF, partN,
                                               cnt, (float*)d_out);
}

// Round 10
// 85.610 us; speedup vs baseline: 2.9665x; 2.9665x over previous
//
#include <hip/hip_runtime.h>
#include <math.h>

// GMMflow_fast: B=2048, M=1024, D=64.  R10 = R8 structure, LDS-minimal main.
//   prep (256 blocks): a,p' bf16 hi/lo -> B1; VT=[K|g] bf16; q f32.
//   main (grid 32x16, 3 blk/CU @ 43.5KB LDS): GEMM1 3-pass bf16 hi/lo K=128,
//     A1=[x^2|x] built in-kernel (LDS); B1 frags read DIRECT from global (L2-res).
//     w=exp(clip(-0.5*(C1+q)))*Lam; norm=shfl-reduce of bf16(w); W via LDS
//     (C-layout -> A-layout transform). GEMM2 single bf16, V frags direct global.
//     Partials: S1|S2 bf16, norms f32.
//   finalize (256x128): u=(x*S1+S2)/n.
// Lessons: R6 serialized-tail, R7 redundant prep, R9 spin grid-barrier (~100x
// worse than kernel-boundary; launch edges ARE the cheap grid barrier).

#define B_N 2048
#define M_N 1024
#define NSPLIT 16
#define BT 64
#define MS 64

typedef short bf16x8 __attribute__((ext_vector_type(8)));
typedef float f32x4 __attribute__((ext_vector_type(4)));

static __device__ __forceinline__ unsigned short bf16rn(float f) {
    union { float f; unsigned u; } v; v.f = f;
    unsigned r = v.u + 0x7FFF + ((v.u >> 16) & 1);
    return (unsigned short)(r >> 16);
}
static __device__ __forceinline__ float bf2f(unsigned short h) {
    union { unsigned u; float f; } v; v.u = ((unsigned)h) << 16;
    return v.f;
}
static __device__ __forceinline__ void st4(unsigned short* p, unsigned short a,
                                           unsigned short b, unsigned short c, unsigned short d) {
    union { unsigned short u[4]; float2 f; } t;
    t.u[0] = a; t.u[1] = b; t.u[2] = c; t.u[3] = d;
    *(float2*)p = t.f;
}

// ---------------- prep: 256 blocks x 4 m, 1 (m,d) pair per thread ----------------
__global__ __launch_bounds__(256)
void prep_kernel(const float* __restrict__ Mu0, const float* __restrict__ Mu1,
                 const float* __restrict__ S0, const float* __restrict__ S1,
                 const float* __restrict__ T, const float* __restrict__ E,
                 unsigned short* __restrict__ B1h, unsigned short* __restrict__ B1l,
                 unsigned short* __restrict__ VTh, float* __restrict__ qArr) {
    __shared__ float sK[4 * 65];
    __shared__ float sG[4 * 65];
    const int tid = threadIdx.x;
    const int m0 = blockIdx.x * 4;
    const int mi = tid >> 6, d = tid & 63;
    const int m = m0 + mi;
    const float t = T[0], e = E[0];
    const float eps2 = e * e, eps4 = eps2 * eps2, omt = 1.f - t;
    int idx = m * 64 + d;
    float s0 = S0[idx], s1 = S1[idx];
    float mu0 = Mu0[idx], mu1 = Mu1[idx];
    float Ds = sqrtf(4.f * s0 * s1 + eps4);
    float Cs = 0.5f * (Ds - eps2);
    float sig = omt * omt * s0 + t * t * s1 + 2.f * t * omt * (Cs + 0.5f * eps2);
    float St = (t * s1 + omt * Cs) - (omt * s0 + t * Cs) - eps2 * t;
    float a = 1.f / sig;
    float K = St * a;
    float mut = omt * mu0 + t * mu1;
    float pp = -2.f * mut * a;
    float g = (mu1 - mu0) - K * mut;
    unsigned short ah = bf16rn(a);
    B1h[m * 128 + d] = ah;
    B1l[m * 128 + d] = bf16rn(a - bf2f(ah));
    unsigned short ph = bf16rn(pp);
    B1h[m * 128 + 64 + d] = ph;
    B1l[m * 128 + 64 + d] = bf16rn(pp - bf2f(ph));
    sK[mi * 65 + d] = K;
    sG[mi * 65 + d] = g;
    float qd = mut * mut * a + __logf(sig);
    #pragma unroll
    for (int off = 32; off > 0; off >>= 1) qd += __shfl_xor(qd, off, 64);
    if (d == 0) qArr[m] = qd;
    __syncthreads();
    // VT[n][m] transpose write: 128 n x 4 m
    #pragma unroll
    for (int it = 0; it < 2; it++) {
        int i = it * 256 + tid;
        int n = i >> 2, mm = i & 3;
        float v = (n < 64) ? sK[mm * 65 + n] : sG[mm * 65 + (n - 64)];
        VTh[n * M_N + m0 + mm] = bf16rn(v);
    }
}

// ---------------- main: grid (32,16), 256 thr, 43.5 KB LDS, 3 blocks/CU ----------------
__global__ __launch_bounds__(256, 2)
void gmm_main_kernel(const float* __restrict__ X, const float* __restrict__ Lam,
                     const unsigned short* __restrict__ B1h, const unsigned short* __restrict__ B1l,
                     const unsigned short* __restrict__ VTh,
                     const float* __restrict__ qArr,
                     unsigned short* __restrict__ partBF, float* __restrict__ partN) {
    // LDS: sA1h[64x136] | sA1l[64x136] | sW[64x72] | sQ[64] | sL[64]  = 44.5 KB
    __shared__ __align__(16) char smem_raw[44544];
    unsigned short* sm = (unsigned short*)smem_raw;
    unsigned short* sA1h = sm;                // 8704 us
    unsigned short* sA1l = sm + 8704;         // 8704 us
    unsigned short* sW   = sm + 17408;        // 4608 us
    float* sQ = (float*)(smem_raw + 44032);
    float* sL = (float*)(smem_raw + 44288);

    const int tid  = threadIdx.x;
    const int Boff = blockIdx.x * BT;
    const int Moff = blockIdx.y * MS;
    const int w    = tid >> 6;
    const int lane = tid & 63;
    const int c = lane & 15, q = lane >> 4;
    const int wb = w >> 1;     // b-half
    const int wm = w & 1;      // GEMM1 m-half / GEMM2 n-half

    // ---- stage A1 from X (hi/lo of x^2, x) into LDS; q/Lam to LDS ----
    {
        const float4* X4 = (const float4*)X;
        #pragma unroll
        for (int it = 0; it < 4; it++) {
            int i = it * 256 + tid;            // 64 b x 16 f4
            int b = i >> 4, dq4 = i & 15;
            float4 xv = X4[(size_t)(Boff + b) * 16 + dq4];
            float xs[4] = {xv.x, xv.y, xv.z, xv.w};
            unsigned short yh[4], yl[4], xh[4], xl[4];
            #pragma unroll
            for (int k = 0; k < 4; k++) {
                float y = xs[k] * xs[k];
                yh[k] = bf16rn(y);  yl[k] = bf16rn(y - bf2f(yh[k]));
                xh[k] = bf16rn(xs[k]);  xl[k] = bf16rn(xs[k] - bf2f(xh[k]));
            }
            int base = b * 136 + 4 * dq4;
            st4(sA1h + base, yh[0], yh[1], yh[2], yh[3]);
            st4(sA1l + base, yl[0], yl[1], yl[2], yl[3]);
            st4(sA1h + base + 64, xh[0], xh[1], xh[2], xh[3]);
            st4(sA1l + base + 64, xl[0], xl[1], xl[2], xl[3]);
        }
        if (tid < 64) sQ[tid] = qArr[Moff + tid];
        else if (tid < 128) sL[tid - 64] = Lam[Moff + tid - 64];
    }
    __syncthreads();

    // ---- GEMM1: wave quadrant 32b x 32m, K=128, 3 hi/lo passes ----
    // A frags from LDS; B frags DIRECT from global (L2-resident, 16B/lane).
    f32x4 acc1[2][2];
    #pragma unroll
    for (int i = 0; i < 2; i++)
        #pragma unroll
        for (int j = 0; j < 2; j++) acc1[i][j] = (f32x4){0.f, 0.f, 0.f, 0.f};
    {
        const unsigned short* gBh = B1h + (size_t)Moff * 128;
        const unsigned short* gBl = B1l + (size_t)Moff * 128;
        #pragma unroll
        for (int ks = 0; ks < 4; ks++) {
            bf16x8 Ah[2], Al[2], Bh[2], Bl[2];
            #pragma unroll
            for (int j = 0; j < 2; j++) {
                int row = wm * 32 + j * 16 + c;
                Bh[j] = *(const bf16x8*)(gBh + row * 128 + ks * 32 + q * 8);
                Bl[j] = *(const bf16x8*)(gBl + row * 128 + ks * 32 + q * 8);
            }
            #pragma unroll
            for (int i = 0; i < 2; i++) {
                int row = wb * 32 + i * 16 + c;
                Ah[i] = *(const bf16x8*)(sA1h + row * 136 + ks * 32 + q * 8);
                Al[i] = *(const bf16x8*)(sA1l + row * 136 + ks * 32 + q * 8);
            }
            #pragma unroll
            for (int i = 0; i < 2; i++)
                #pragma unroll
                for (int j = 0; j < 2; j++) {
                    acc1[i][j] = __builtin_amdgcn_mfma_f32_16x16x32_bf16(Ah[i], Bh[j], acc1[i][j], 0, 0, 0);
                    acc1[i][j] = __builtin_amdgcn_mfma_f32_16x16x32_bf16(Ah[i], Bl[j], acc1[i][j], 0, 0, 0);
                    acc1[i][j] = __builtin_amdgcn_mfma_f32_16x16x32_bf16(Al[i], Bh[j], acc1[i][j], 0, 0, 0);
                }
        }
    }

    // ---- W = exp(clip(-0.5*(C1+q)))*Lam -> sW (A-layout) + consistent norm ----
    {
        float nsum[2][4];
        #pragma unroll
        for (int i = 0; i < 2; i++)
            #pragma unroll
            for (int r = 0; r < 4; r++) nsum[i][r] = 0.f;
        #pragma unroll
        for (int i = 0; i < 2; i++)
            #pragma unroll
            for (int j = 0; j < 2; j++) {
                int m = wm * 32 + j * 16 + c;
                float qm = sQ[m], lm = sL[m];
                #pragma unroll
                for (int r = 0; r < 4; r++) {
                    int bl = wb * 32 + i * 16 + q * 4 + r;
                    float lw = -0.5f * (acc1[i][j][r] + qm);
                    lw = fminf(50.f, fmaxf(-50.f, lw));
                    float wf = __expf(lw) * lm;
                    unsigned short wh = bf16rn(wf);
                    sW[bl * 72 + m] = wh;
                    nsum[i][r] += bf2f(wh);
                }
            }
        #pragma unroll
        for (int mask = 1; mask <= 8; mask <<= 1)
            #pragma unroll
            for (int i = 0; i < 2; i++)
                #pragma unroll
                for (int r = 0; r < 4; r++)
                    nsum[i][r] += __shfl_xor(nsum[i][r], mask, 64);
        if (c == 0) {
            #pragma unroll
            for (int i = 0; i < 2; i++)
                #pragma unroll
                for (int r = 0; r < 4; r++) {
                    int b = Boff + wb * 32 + i * 16 + q * 4 + r;
                    partN[((size_t)blockIdx.y * B_N + b) * 2 + wm] = nsum[i][r];
                }
        }
    }
    __syncthreads();

    // ---- GEMM2: wave 32b x 64n, K=64, single pass; V frags direct from global ----
    f32x4 acc2[2][4];
    #pragma unroll
    for (int i = 0; i < 2; i++)
        #pragma unroll
        for (int j = 0; j < 4; j++) acc2[i][j] = (f32x4){0.f, 0.f, 0.f, 0.f};
    #pragma unroll
    for (int ks = 0; ks < 2; ks++) {
        bf16x8 Wf[2], Vf[4];
        #pragma unroll
        for (int j = 0; j < 4; j++) {
            int row = wm * 64 + j * 16 + c;
            Vf[j] = *(const bf16x8*)(VTh + (size_t)row * M_N + Moff + ks * 32 + q * 8);
        }
        #pragma unroll
        for (int i = 0; i < 2; i++) {
            int row = wb * 32 + i * 16 + c;
            Wf[i] = *(const bf16x8*)(sW + row * 72 + ks * 32 + q * 8);
        }
        #pragma unroll
        for (int i = 0; i < 2; i++)
            #pragma unroll
            for (int j = 0; j < 4; j++)
                acc2[i][j] = __builtin_amdgcn_mfma_f32_16x16x32_bf16(Wf[i], Vf[j], acc2[i][j], 0, 0, 0);
    }

    // ---- partial S1|S2 writes (bf16) ----
    #pragma unroll
    for (int i = 0; i < 2; i++)
        #pragma unroll
        for (int j = 0; j < 4; j++) {
            #pragma unroll
            for (int r = 0; r < 4; r++) {
                int b = Boff + wb * 32 + i * 16 + q * 4 + r;
                int n = wm * 64 + j * 16 + c;
                partBF[((size_t)blockIdx.y * B_N + b) * 128 + n] = bf16rn(acc2[i][j][r]);
            }
        }
}

// ---------------- finalize: 256 blocks x 128, thread per (b, d-quad) ----------------
__global__ __launch_bounds__(128)
void finalize_kernel(const float* __restrict__ X, const unsigned short* __restrict__ partBF,
                     const float* __restrict__ partN, float* __restrict__ out) {
    int gid = blockIdx.x * 128 + threadIdx.x;   // 32768 = 2048 b x 16 quads
    int b = gid >> 4, d0 = (gid & 15) * 4;
    float a1[4] = {0.f, 0.f, 0.f, 0.f}, a2[4] = {0.f, 0.f, 0.f, 0.f}, nn = 0.f;
    #pragma unroll
    for (int s = 0; s < NSPLIT; s++) {
        const unsigned short* row = partBF + ((size_t)s * B_N + b) * 128;
        ushort4 v1 = *(const ushort4*)(row + d0);
        ushort4 v2 = *(const ushort4*)(row + 64 + d0);
        a1[0] += bf2f(v1.x); a1[1] += bf2f(v1.y); a1[2] += bf2f(v1.z); a1[3] += bf2f(v1.w);
        a2[0] += bf2f(v2.x); a2[1] += bf2f(v2.y); a2[2] += bf2f(v2.z); a2[3] += bf2f(v2.w);
        float2 nv = *(const float2*)(partN + ((size_t)s * B_N + b) * 2);
        nn += nv.x + nv.y;
    }
    float rn = 1.f / nn;
    float4 xv = *(const float4*)(X + (size_t)b * 64 + d0);
    float4 o;
    o.x = (xv.x * a1[0] + a2[0]) * rn;
    o.y = (xv.y * a1[1] + a2[1]) * rn;
    o.z = (xv.z * a1[2] + a2[2]) * rn;
    o.w = (xv.w * a1[3] + a2[3]) * rn;
    *(float4*)(out + (size_t)b * 64 + d0) = o;
}

extern "C" void kernel_launch(void* const* d_in, const int* in_sizes, int n_in,
                              void* d_out, int out_size, void* d_ws, size_t ws_size,
                              hipStream_t stream) {
    (void)in_sizes; (void)n_in; (void)out_size; (void)ws_size;
    const float* X   = (const float*)d_in[0];
    const float* Mu0 = (const float*)d_in[1];
    const float* Mu1 = (const float*)d_in[2];
    const float* S0  = (const float*)d_in[3];
    const float* S1  = (const float*)d_in[4];
    const float* Lam = (const float*)d_in[5];
    const float* T   = (const float*)d_in[6];
    const float* E   = (const float*)d_in[7];

    char* ws = (char*)d_ws;
    unsigned short* B1h   = (unsigned short*)(ws);              // 256 KB
    unsigned short* B1l   = (unsigned short*)(ws + 262144);     // 256 KB
    unsigned short* VTh   = (unsigned short*)(ws + 524288);     // 256 KB
    float*          qArr  = (float*)(ws + 786432);              // 4 KB
    unsigned short* partBF= (unsigned short*)(ws + 790528);     // 8.39 MB
    float*          partN = (float*)(ws + 790528 + 8388608);    // 512 KB

    prep_kernel<<<256, 256, 0, stream>>>(Mu0, Mu1, S0, S1, T, E, B1h, B1l, VTh, qArr);
    dim3 grid(B_N / BT, NSPLIT);
    gmm_main_kernel<<<grid, 256, 0, stream>>>(X, Lam, B1h, B1l, VTh, qArr, partBF, partN);
    finalize_kernel<<<256, 128, 0, stream>>>(X, partBF, partN, (float*)d_out);
}

// Round 11
// 82.751 us; speedup vs baseline: 3.0689x; 1.0345x over previous
//
#include <hip/hip_runtime.h>
#include <math.h>

// GMMflow_fast: B=2048, M=1024, D=64.  R11 = R8 exact revert (measured best:
// 83.67 us, absmax 0.03125).
//   prep (256 blocks): a=1/Sigma, p'=-2*mut*a (bf16 hi/lo), VT=[K|g] bf16, q[m] f32.
//   main (grid 32x16, 2 blk/CU): GEMM1 3-pass bf16 hi/lo K=128 (A1=[x^2|x] built
//     in-kernel, B1=[a|p']); w=exp(clip(-0.5*(C1+q)))*Lam; norm via shfl of
//     bf16-rounded w (consistent with GEMM2's W); GEMM2 single bf16 K=64m.
//     Partials: S1|S2 as bf16 (halves traffic; norms f32 — common-mode per b).
//   finalize (256 blocks x 128): reduce 16 splits, u=(x*S1+S2)/n.
// Falsified variants (keep for the record): R6 fused-tail reduction (+41 us,
// 32-block serialized 17MB fetch); R7 inline per-block prep (+13, 32x redundant);
// R9 spin grid-barrier (+170, cross-XCD counter polling throttles all CUs);
// R10 direct-global MFMA frags (+1.9, 16-row gather per lane-load beats LDS never).

#define B_N 2048
#define M_N 1024
#define NSPLIT 16
#define BT 64
#define MS 64

typedef short bf16x8 __attribute__((ext_vector_type(8)));
typedef float f32x4 __attribute__((ext_vector_type(4)));

static __device__ __forceinline__ unsigned short bf16rn(float f) {
    union { float f; unsigned u; } v; v.f = f;
    unsigned r = v.u + 0x7FFF + ((v.u >> 16) & 1);
    return (unsigned short)(r >> 16);
}
static __device__ __forceinline__ float bf2f(unsigned short h) {
    union { unsigned u; float f; } v; v.u = ((unsigned)h) << 16;
    return v.f;
}
static __device__ __forceinline__ void st4(unsigned short* p, unsigned short a,
                                           unsigned short b, unsigned short c, unsigned short d) {
    union { unsigned short u[4]; float2 f; } t;
    t.u[0] = a; t.u[1] = b; t.u[2] = c; t.u[3] = d;
    *(float2*)p = t.f;
}

// ---------------- prep: 256 blocks x 4 m, 1 (m,d) pair per thread ----------------
__global__ __launch_bounds__(256)
void prep_kernel(const float* __restrict__ Mu0, const float* __restrict__ Mu1,
                 const float* __restrict__ S0, const float* __restrict__ S1,
                 const float* __restrict__ T, const float* __restrict__ E,
                 unsigned short* __restrict__ B1h, unsigned short* __restrict__ B1l,
                 unsigned short* __restrict__ VTh, float* __restrict__ qArr) {
    __shared__ float sK[4 * 65];
    __shared__ float sG[4 * 65];
    const int tid = threadIdx.x;
    const int m0 = blockIdx.x * 4;
    const int mi = tid >> 6, d = tid & 63;
    const int m = m0 + mi;
    const float t = T[0], e = E[0];
    const float eps2 = e * e, eps4 = eps2 * eps2, omt = 1.f - t;
    int idx = m * 64 + d;
    float s0 = S0[idx], s1 = S1[idx];
    float mu0 = Mu0[idx], mu1 = Mu1[idx];
    float Ds = sqrtf(4.f * s0 * s1 + eps4);
    float Cs = 0.5f * (Ds - eps2);
    float sig = omt * omt * s0 + t * t * s1 + 2.f * t * omt * (Cs + 0.5f * eps2);
    float St = (t * s1 + omt * Cs) - (omt * s0 + t * Cs) - eps2 * t;
    float a = 1.f / sig;
    float K = St * a;
    float mut = omt * mu0 + t * mu1;
    float pp = -2.f * mut * a;
    float g = (mu1 - mu0) - K * mut;
    unsigned short ah = bf16rn(a);
    B1h[m * 128 + d] = ah;
    B1l[m * 128 + d] = bf16rn(a - bf2f(ah));
    unsigned short ph = bf16rn(pp);
    B1h[m * 128 + 64 + d] = ph;
    B1l[m * 128 + 64 + d] = bf16rn(pp - bf2f(ph));
    sK[mi * 65 + d] = K;
    sG[mi * 65 + d] = g;
    float qd = mut * mut * a + __logf(sig);
    #pragma unroll
    for (int off = 32; off > 0; off >>= 1) qd += __shfl_xor(qd, off, 64);
    if (d == 0) qArr[m] = qd;
    __syncthreads();
    // VT[n][m] transpose write: 128 n x 4 m
    #pragma unroll
    for (int it = 0; it < 2; it++) {
        int i = it * 256 + tid;
        int n = i >> 2, mm = i & 3;
        float v = (n < 64) ? sK[mm * 65 + n] : sG[mm * 65 + (n - 64)];
        VTh[n * M_N + m0 + mm] = bf16rn(v);
    }
}

// ---------------- main: grid (32,16), 256 thr, ~70 KB LDS, 2 blocks/CU ----------------
__global__ __launch_bounds__(256, 2)
void gmm_main_kernel(const float* __restrict__ X, const float* __restrict__ Lam,
                     const unsigned short* __restrict__ B1h, const unsigned short* __restrict__ B1l,
                     const unsigned short* __restrict__ VTh,
                     const float* __restrict__ qArr,
                     unsigned short* __restrict__ partBF, float* __restrict__ partN) {
    __shared__ __align__(16) char smem_raw[70144];
    unsigned short* sm = (unsigned short*)smem_raw;
    unsigned short* sA1h = sm;                // 8704 us
    unsigned short* sA1l = sm + 8704;
    unsigned short* sB1h = sm + 17408;
    unsigned short* sB1l = sm + 26112;        // region end 34816 us
    unsigned short* sV   = sm;                // overlay on A: 128x72 = 9216 us
    unsigned short* sW   = sm + 17408;        // overlay on B: 64x72 = 4608 us
    float* sQ = (float*)(smem_raw + 69632);
    float* sL = (float*)(smem_raw + 69888);

    const int tid  = threadIdx.x;
    const int Boff = blockIdx.x * BT;
    const int Moff = blockIdx.y * MS;
    const int w    = tid >> 6;
    const int lane = tid & 63;
    const int c = lane & 15, q = lane >> 4;
    const int wb = w >> 1;     // b-half
    const int wm = w & 1;      // GEMM1 m-half / GEMM2 n-half

    // ---- stage A1 from X (hi/lo of x^2, x); copy B1 h/l from global ----
    {
        const float4* X4 = (const float4*)X;
        #pragma unroll
        for (int it = 0; it < 4; it++) {
            int i = it * 256 + tid;            // 64 b x 16 f4
            int b = i >> 4, dq4 = i & 15;
            float4 xv = X4[(size_t)(Boff + b) * 16 + dq4];
            float xs[4] = {xv.x, xv.y, xv.z, xv.w};
            unsigned short yh[4], yl[4], xh[4], xl[4];
            #pragma unroll
            for (int k = 0; k < 4; k++) {
                float y = xs[k] * xs[k];
                yh[k] = bf16rn(y);  yl[k] = bf16rn(y - bf2f(yh[k]));
                xh[k] = bf16rn(xs[k]);  xl[k] = bf16rn(xs[k] - bf2f(xh[k]));
            }
            int base = b * 136 + 4 * dq4;
            st4(sA1h + base, yh[0], yh[1], yh[2], yh[3]);
            st4(sA1l + base, yl[0], yl[1], yl[2], yl[3]);
            st4(sA1h + base + 64, xh[0], xh[1], xh[2], xh[3]);
            st4(sA1l + base + 64, xl[0], xl[1], xl[2], xl[3]);
        }
        const float4* gBh = (const float4*)B1h + (size_t)Moff * 16;
        const float4* gBl = (const float4*)B1l + (size_t)Moff * 16;
        #pragma unroll
        for (int it = 0; it < 4; it++) {
            int i = it * 256 + tid;            // 64 m x 16 f4
            int row = i >> 4, cc = i & 15;
            *(float4*)(sB1h + row * 136 + cc * 8) = gBh[row * 16 + cc];
            *(float4*)(sB1l + row * 136 + cc * 8) = gBl[row * 16 + cc];
        }
        if (tid < 64) sQ[tid] = qArr[Moff + tid];
        else if (tid < 128) sL[tid - 64] = Lam[Moff + tid - 64];
    }
    __syncthreads();

    // ---- GEMM1: wave quadrant 32b x 32m, K=128, 3 hi/lo passes ----
    f32x4 acc1[2][2];
    #pragma unroll
    for (int i = 0; i < 2; i++)
        #pragma unroll
        for (int j = 0; j < 2; j++) acc1[i][j] = (f32x4){0.f, 0.f, 0.f, 0.f};
    #pragma unroll
    for (int ks = 0; ks < 4; ks++) {
        bf16x8 Ah[2], Al[2], Bh[2], Bl[2];
        #pragma unroll
        for (int i = 0; i < 2; i++) {
            int row = wb * 32 + i * 16 + c;
            Ah[i] = *(const bf16x8*)(sA1h + row * 136 + ks * 32 + q * 8);
            Al[i] = *(const bf16x8*)(sA1l + row * 136 + ks * 32 + q * 8);
        }
        #pragma unroll
        for (int j = 0; j < 2; j++) {
            int row = wm * 32 + j * 16 + c;
            Bh[j] = *(const bf16x8*)(sB1h + row * 136 + ks * 32 + q * 8);
            Bl[j] = *(const bf16x8*)(sB1l + row * 136 + ks * 32 + q * 8);
        }
        #pragma unroll
        for (int i = 0; i < 2; i++)
            #pragma unroll
            for (int j = 0; j < 2; j++) {
                acc1[i][j] = __builtin_amdgcn_mfma_f32_16x16x32_bf16(Ah[i], Bh[j], acc1[i][j], 0, 0, 0);
                acc1[i][j] = __builtin_amdgcn_mfma_f32_16x16x32_bf16(Ah[i], Bl[j], acc1[i][j], 0, 0, 0);
                acc1[i][j] = __builtin_amdgcn_mfma_f32_16x16x32_bf16(Al[i], Bh[j], acc1[i][j], 0, 0, 0);
            }
    }
    __syncthreads();   // A/B regions dead -> overlays

    // ---- stage V (bf16) + compute W + consistent norm ----
    {
        const float4* gV = (const float4*)VTh;   // row stride 128 f4
        int mo8 = Moff >> 3;
        #pragma unroll
        for (int it = 0; it < 4; it++) {
            int i = it * 256 + tid;              // 128 n x 8 f4
            int row = i >> 3, cc = i & 7;
            *(float4*)(sV + row * 72 + cc * 8) = gV[(size_t)row * 128 + mo8 + cc];
        }
        float nsum[2][4];
        #pragma unroll
        for (int i = 0; i < 2; i++)
            #pragma unroll
            for (int r = 0; r < 4; r++) nsum[i][r] = 0.f;
        #pragma unroll
        for (int i = 0; i < 2; i++)
            #pragma unroll
            for (int j = 0; j < 2; j++) {
                int m = wm * 32 + j * 16 + c;
                float qm = sQ[m], lm = sL[m];
                #pragma unroll
                for (int r = 0; r < 4; r++) {
                    int bl = wb * 32 + i * 16 + q * 4 + r;
                    float lw = -0.5f * (acc1[i][j][r] + qm);
                    lw = fminf(50.f, fmaxf(-50.f, lw));
                    float wf = __expf(lw) * lm;
                    unsigned short wh = bf16rn(wf);
                    sW[bl * 72 + m] = wh;
                    nsum[i][r] += bf2f(wh);
                }
            }
        #pragma unroll
        for (int mask = 1; mask <= 8; mask <<= 1)
            #pragma unroll
            for (int i = 0; i < 2; i++)
                #pragma unroll
                for (int r = 0; r < 4; r++)
                    nsum[i][r] += __shfl_xor(nsum[i][r], mask, 64);
        if (c == 0) {
            #pragma unroll
            for (int i = 0; i < 2; i++)
                #pragma unroll
                for (int r = 0; r < 4; r++) {
                    int b = Boff + wb * 32 + i * 16 + q * 4 + r;
                    partN[((size_t)blockIdx.y * B_N + b) * 2 + wm] = nsum[i][r];
                }
        }
    }
    __syncthreads();

    // ---- GEMM2: wave 32b x 64n, K=64, single pass ----
    f32x4 acc2[2][4];
    #pragma unroll
    for (int i = 0; i < 2; i++)
        #pragma unroll
        for (int j = 0; j < 4; j++) acc2[i][j] = (f32x4){0.f, 0.f, 0.f, 0.f};
    #pragma unroll
    for (int ks = 0; ks < 2; ks++) {
        bf16x8 Wf[2], Vf[4];
        #pragma unroll
        for (int i = 0; i < 2; i++) {
            int row = wb * 32 + i * 16 + c;
            Wf[i] = *(const bf16x8*)(sW + row * 72 + ks * 32 + q * 8);
        }
        #pragma unroll
        for (int j = 0; j < 4; j++) {
            int row = wm * 64 + j * 16 + c;
            Vf[j] = *(const bf16x8*)(sV + row * 72 + ks * 32 + q * 8);
        }
        #pragma unroll
        for (int i = 0; i < 2; i++)
            #pragma unroll
            for (int j = 0; j < 4; j++)
                acc2[i][j] = __builtin_amdgcn_mfma_f32_16x16x32_bf16(Wf[i], Vf[j], acc2[i][j], 0, 0, 0);
    }

    // ---- partial S1|S2 writes (bf16) ----
    #pragma unroll
    for (int i = 0; i < 2; i++)
        #pragma unroll
        for (int j = 0; j < 4; j++) {
            #pragma unroll
            for (int r = 0; r < 4; r++) {
                int b = Boff + wb * 32 + i * 16 + q * 4 + r;
                int n = wm * 64 + j * 16 + c;
                partBF[((size_t)blockIdx.y * B_N + b) * 128 + n] = bf16rn(acc2[i][j][r]);
            }
        }
}

// ---------------- finalize: 256 blocks x 128, thread per (b, d-quad) ----------------
__global__ __launch_bounds__(128)
void finalize_kernel(const float* __restrict__ X, const unsigned short* __restrict__ partBF,
                     const float* __restrict__ partN, float* __restrict__ out) {
    int gid = blockIdx.x * 128 + threadIdx.x;   // 32768 = 2048 b x 16 quads
    int b = gid >> 4, d0 = (gid & 15) * 4;
    float a1[4] = {0.f, 0.f, 0.f, 0.f}, a2[4] = {0.f, 0.f, 0.f, 0.f}, nn = 0.f;
    #pragma unroll
    for (int s = 0; s < NSPLIT; s++) {
        const unsigned short* row = partBF + ((size_t)s * B_N + b) * 128;
        ushort4 v1 = *(const ushort4*)(row + d0);
        ushort4 v2 = *(const ushort4*)(row + 64 + d0);
        a1[0] += bf2f(v1.x); a1[1] += bf2f(v1.y); a1[2] += bf2f(v1.z); a1[3] += bf2f(v1.w);
        a2[0] += bf2f(v2.x); a2[1] += bf2f(v2.y); a2[2] += bf2f(v2.z); a2[3] += bf2f(v2.w);
        float2 nv = *(const float2*)(partN + ((size_t)s * B_N + b) * 2);
        nn += nv.x + nv.y;
    }
    float rn = 1.f / nn;
    float4 xv = *(const float4*)(X + (size_t)b * 64 + d0);
    float4 o;
    o.x = (xv.x * a1[0] + a2[0]) * rn;
    o.y = (xv.y * a1[1] + a2[1]) * rn;
    o.z = (xv.z * a1[2] + a2[2]) * rn;
    o.w = (xv.w * a1[3] + a2[3]) * rn;
    *(float4*)(out + (size_t)b * 64 + d0) = o;
}

extern "C" void kernel_launch(void* const* d_in, const int* in_sizes, int n_in,
                              void* d_out, int out_size, void* d_ws, size_t ws_size,
                              hipStream_t stream) {
    (void)in_sizes; (void)n_in; (void)out_size; (void)ws_size;
    const float* X   = (const float*)d_in[0];
    const float* Mu0 = (const float*)d_in[1];
    const float* Mu1 = (const float*)d_in[2];
    const float* S0  = (const float*)d_in[3];
    const float* S1  = (const float*)d_in[4];
    const float* Lam = (const float*)d_in[5];
    const float* T   = (const float*)d_in[6];
    const float* E   = (const float*)d_in[7];

    char* ws = (char*)d_ws;
    unsigned short* B1h   = (unsigned short*)(ws);              // 256 KB
    unsigned short* B1l   = (unsigned short*)(ws + 262144);     // 256 KB
    unsigned short* VTh   = (unsigned short*)(ws + 524288);     // 256 KB
    float*          qArr  = (float*)(ws + 786432);              // 4 KB
    unsigned short* partBF= (unsigned short*)(ws + 790528);     // 8.39 MB
    float*          partN = (float*)(ws + 790528 + 8388608);    // 512 KB

    prep_kernel<<<256, 256, 0, stream>>>(Mu0, Mu1, S0, S1, T, E, B1h, B1l, VTh, qArr);
    dim3 grid(B_N / BT, NSPLIT);
    gmm_main_kernel<<<grid, 256, 0, stream>>>(X, Lam, B1h, B1l, VTh, qArr, partBF, partN);
    finalize_kernel<<<256, 128, 0, stream>>>(X, partBF, partN, (float*)d_out);
}